// Round 16
// baseline (167.899 us; speedup 1.0000x reference)
//
#include <hip/hip_runtime.h>
#include <hip/hip_bf16.h>

typedef short s16x8 __attribute__((ext_vector_type(8)));
typedef float f32x2 __attribute__((ext_vector_type(2)));
typedef float f32x4 __attribute__((ext_vector_type(4)));
typedef float f32x16 __attribute__((ext_vector_type(16)));
typedef unsigned int u32;
typedef unsigned short u16;
typedef u32 u32x4v __attribute__((ext_vector_type(4)));

#define TOK 216
#define T1 448
#define SP 110592
// fallback LDS map
#define BUF0 0
#define VOFF 57344
#define WOFF 122880
#define GBOFF 155648
#define LDS_OLD 157696
// attnh LDS map: KH [224 rows x 128B] then obuf; VHOFF Vraw(27KB)->Vt 64x512B
#define VHOFF 28672
#define TENB 28311552ull
#define WSNEED (3ull*TENB + 32768ull)
#define QSCALE 0.360673760f // 0.25 * log2(e): scores*log2e -> exp2

__device__ __forceinline__ u32 pack2(float a, float b) {
  u16 lo = __builtin_bit_cast(u16, __float2bfloat16(a));
  u16 hi = __builtin_bit_cast(u16, __float2bfloat16(b));
  return (u32)lo | ((u32)hi << 16);
}
__device__ __forceinline__ int swz(int row, int inner) {
  return inner ^ ((row & 7) << 4);
}
__device__ __forceinline__ void gload16(const void* g, void* l) {
  __builtin_amdgcn_global_load_lds(
      (const __attribute__((address_space(1))) void*)g,
      (__attribute__((address_space(3))) void*)l, 16, 0, 0);
}

__device__ __forceinline__ void ln_stats(const f32x2* xv, float& mA, float& rA,
                                         float& mB, float& rB) {
  float sA = 0.f, s2A = 0.f, sB = 0.f, s2B = 0.f;
#pragma unroll
  for (int c = 0; c < 32; ++c) {
    sA += xv[c].x; s2A += xv[c].x * xv[c].x;
    sB += xv[c].y; s2B += xv[c].y * xv[c].y;
  }
  sA += __shfl_xor(sA, 1); s2A += __shfl_xor(s2A, 1);
  sB += __shfl_xor(sB, 1); s2B += __shfl_xor(s2B, 1);
  sA += __shfl_xor(sA, 2); s2A += __shfl_xor(s2A, 2);
  sB += __shfl_xor(sB, 2); s2B += __shfl_xor(s2B, 2);
  mA = sA * (1.0f / 128.0f);
  rA = rsqrtf(s2A * (1.0f / 128.0f) - mA * mA + 1e-5f);
  mB = sB * (1.0f / 128.0f);
  rB = rsqrtf(s2B * (1.0f / 128.0f) - mB * mB + 1e-5f);
}

// attnh step: head-half tiles (K rows 128B, V-half 64 ch-rows). Verified
// r6-r15 math with half-width indexing. No-max softmax (exp2, log2e in Q);
// sigma-permuted V so packed P regs ARE the PV B-fragments.
template<bool MASK>
__device__ __forceinline__ void attn_stepH(const char* smem, int jloc, int kt,
                                           s16x8 qfh, int lane,
                                           f32x16& acc, float& lsum) {
  const int half = lane >> 5;
  const int krow = kt * 32 + (lane & 31);
  s16x8 kf = *(const s16x8*)(smem + krow * 128 +
                             ((jloc * 32 + half * 16) ^ ((krow & 7) << 4)));
  f32x16 st = __builtin_amdgcn_mfma_f32_32x32x16_bf16(kf, qfh, (f32x16){}, 0, 0, 0);
  const int vrow = jloc * 16 + (lane & 15);
  s16x8 vf0 = *(const s16x8*)(smem + VHOFF + vrow * 512 +
                              ((kt * 64 + half * 16) ^ ((vrow & 7) << 4)));
  s16x8 vf1 = *(const s16x8*)(smem + VHOFF + vrow * 512 +
                              ((kt * 64 + 32 + half * 16) ^ ((vrow & 7) << 4)));
  const int NR = MASK ? 12 : 16;
  u32 A[8];
  float ts0 = 0.f, ts1 = 0.f;
#pragma unroll
  for (int i = 0; i < 8; ++i) {
    float p0 = (2 * i < NR) ? __builtin_amdgcn_exp2f(st[2 * i]) : 0.f;
    float p1 = (2 * i + 1 < NR) ? __builtin_amdgcn_exp2f(st[2 * i + 1]) : 0.f;
    if (i & 1) ts1 += p0 + p1; else ts0 += p0 + p1;
    A[i] = pack2(p0, p1);
  }
  lsum += ts0 + ts1;
  s16x8 pf0 = __builtin_bit_cast(s16x8, (u32x4v){A[0], A[1], A[2], A[3]});
  s16x8 pf1 = __builtin_bit_cast(s16x8, (u32x4v){A[4], A[5], A[6], A[7]});
  acc = __builtin_amdgcn_mfma_f32_32x32x16_bf16(vf0, pf0, acc, 0, 0, 0);
  acc = __builtin_amdgcn_mfma_f32_32x32x16_bf16(vf1, pf1, acc, 0, 0, 0);
}

// fallback step (verified r6-r15)
template<bool MASK>
__device__ __forceinline__ void attn_stepF(const char* smem, int h, int kt,
                                           s16x8 qfh, int lane,
                                           f32x16& acc, float& lsum) {
  const int half = lane >> 5;
  const int krow = kt * 32 + (lane & 31);
  s16x8 kf = *(const s16x8*)(smem + BUF0 + krow * 256 +
                             swz(krow, h * 32 + half * 16));
  f32x16 st = __builtin_amdgcn_mfma_f32_32x32x16_bf16(kf, qfh, (f32x16){}, 0, 0, 0);
  const int vrow = h * 16 + (lane & 15);
  s16x8 vf0 = *(const s16x8*)(smem + VOFF + vrow * 512 +
                              swz(vrow, kt * 64 + half * 16));
  s16x8 vf1 = *(const s16x8*)(smem + VOFF + vrow * 512 +
                              swz(vrow, kt * 64 + 32 + half * 16));
  const int NR = MASK ? 12 : 16;
  u32 A[8];
  float ts0 = 0.f, ts1 = 0.f;
#pragma unroll
  for (int i = 0; i < 8; ++i) {
    float p0 = (2 * i < NR) ? __builtin_amdgcn_exp2f(st[2 * i]) : 0.f;
    float p1 = (2 * i + 1 < NR) ? __builtin_amdgcn_exp2f(st[2 * i + 1]) : 0.f;
    if (i & 1) ts1 += p0 + p1; else ts0 += p0 + p1;
    A[i] = pack2(p0, p1);
  }
  lsum += ts0 + ts1;
  s16x8 pf0 = __builtin_bit_cast(s16x8, (u32x4v){A[0], A[1], A[2], A[3]});
  s16x8 pf1 = __builtin_bit_cast(s16x8, (u32x4v){A[4], A[5], A[6], A[7]});
  acc = __builtin_amdgcn_mfma_f32_32x32x16_bf16(vf0, pf0, acc, 0, 0, 0);
  acc = __builtin_amdgcn_mfma_f32_32x32x16_bf16(vf1, pf1, acc, 0, 0, 0);
}

// ================= Kernel 1: zero-LDS max-occupancy LN ======================
// 2592 blocks x 128 thr, ZERO LDS -> thread-capped 16 blocks/CU (32 waves/CU,
// 5.6x r15's residency -> the MLP needed to cover ~900ns HBM latency).
// lane = token: coalesced 256B reads; stats lane-local; output row of each
// token is 256B contiguous -> direct dwordx4 stores at 256B lane stride
// (16-instruction group fully covers the span; L2 write-combines).
extern "C" __global__ __launch_bounds__(128)
void lnpre_kernel(const float* __restrict__ qm, const float* __restrict__ km,
                  const float* __restrict__ vm,
                  const float* __restrict__ gq, const float* __restrict__ bq,
                  const float* __restrict__ gkv, const float* __restrict__ bkv,
                  const float* __restrict__ pw,
                  u16* __restrict__ qn, u16* __restrict__ kn,
                  u16* __restrict__ vn, u16* __restrict__ wbf) {
  const int tid = threadIdx.x;
  const int bid = blockIdx.x;
  if (bid >= 2592) {            // W conversion: 16384 f32 -> bf16
#pragma unroll
    for (int k = 0; k < 64; ++k) {
      int idx = tid + 128 * k;
      f32x2 w2 = *(const f32x2*)(pw + idx * 2);
      ((u32*)wbf)[idx] = pack2(w2.x, w2.y);
    }
    return;
  }
  const int lane = tid & 63, wv = tid >> 6;
  const int t = bid / 864, rb = bid - t * 864;
  const float* src = t == 0 ? qm : (t == 1 ? km : vm);
  u16* dst = t == 0 ? qn : (t == 1 ? kn : vn);
  const float* g = (t == 0) ? gq : gkv;
  const float* b = (t == 0) ? bq : bkv;
  const float scale = (t == 0) ? QSCALE : 1.0f;
  const long T0 = (long)(rb * 2 + wv) * 64;
  const float* base = src + T0 + lane;

  // pass 1: stats, 4 partial accumulators (lane-local; 128 independent loads)
  float s0 = 0.f, s1 = 0.f, s2 = 0.f, s3 = 0.f;
  float q0 = 0.f, q1 = 0.f, q2 = 0.f, q3 = 0.f;
#pragma unroll 8
  for (int c = 0; c < 128; c += 4) {
    float x0 = base[(long)(c + 0) * SP];
    float x1 = base[(long)(c + 1) * SP];
    float x2 = base[(long)(c + 2) * SP];
    float x3 = base[(long)(c + 3) * SP];
    s0 += x0; q0 += x0 * x0; s1 += x1; q1 += x1 * x1;
    s2 += x2; q2 += x2 * x2; s3 += x3; q3 += x3 * x3;
  }
  float s = (s0 + s1) + (s2 + s3);
  float sq = (q0 + q1) + (q2 + q3);
  float m = s * (1.f / 128.f);
  float r = rsqrtf(sq * (1.f / 128.f) - m * m + 1e-5f);
  // stop the compiler CSE-ing pass2 loads with pass1 (would keep 128 live regs)
  asm volatile("" ::: "memory");

  // pass 2: re-read (cache-hot), LN, pack, store directly (token row = 256B)
  u16* drow = dst + (T0 + lane) * 128;
#pragma unroll 4
  for (int ch8 = 0; ch8 < 16; ++ch8) {
    u32x4v pk;
#pragma unroll
    for (int e = 0; e < 4; ++e) {
      int c = ch8 * 8 + e * 2;
      float x0 = base[(long)c * SP];
      float x1 = base[(long)(c + 1) * SP];
      pk[e] = pack2(((x0 - m) * r * g[c] + b[c]) * scale,
                    ((x1 - m) * r * g[c + 1] + b[c + 1]) * scale);
    }
    *(u32x4v*)(drow + ch8 * 8) = pk;
  }
}

// ================= Kernel 2: attention, (window x head-half) blocks =========
// 1024 blocks x 448 threads, 61440B LDS -> 2 blocks/CU. O-half streamed
// coalesced into qn in-place (block only overwrites rows/bytes only it reads).
extern "C" __global__ __launch_bounds__(448, 4)
void attnh_kernel(u16* __restrict__ qn, const u16* __restrict__ kn,
                  const u16* __restrict__ vn) {
  __shared__ __align__(16) char smem[61440];
  const int tid = threadIdx.x, lane = tid & 63, wv = tid >> 6;
  const int half = lane >> 5;
  const int bid = blockIdx.x;
  const int wid = bid >> 1, hg = bid & 1;
  const int wd6 = (wid >> 6) * 6, wh6 = ((wid >> 3) & 7) * 6, ww6 = (wid & 7) * 6;

  // stage K-half (swz-src, 8 rows x 128B per unit)
  for (int uu = wv; uu < 27; uu += 7) {
    int row = 8 * uu + (lane >> 3);
    int tq = row / 6;
    int g = (wd6 + tq / 6) * 2304 + (wh6 + tq % 6) * 48 + ww6 + row % 6;
    gload16(kn + g * 128 + hg * 64 + (((lane & 7) ^ (row & 7)) << 3),
            smem + uu * 1024);
  }
  // stage V-half raw (linear rows [tok][64ch])
  for (int uu = wv; uu < 27; uu += 7) {
    int row = 8 * uu + (lane >> 3);
    int tq = row / 6;
    int g = (wd6 + tq / 6) * 2304 + (wh6 + tq % 6) * 48 + ww6 + row % 6;
    gload16(vn + g * 128 + hg * 64 + ((lane & 7) << 3),
            smem + VHOFF + uu * 1024);
  }
  // Q fragments direct from global (drain overlaps K/V staging)
  int qrow = wv * 32 + (lane & 31);
  if (qrow > 215) qrow = 215;
  int qtq = qrow / 6;
  int qg = (wd6 + qtq / 6) * 2304 + (wh6 + qtq % 6) * 48 + ww6 + qrow % 6;
  s16x8 qf[4];
#pragma unroll
  for (int j = 0; j < 4; ++j)
    qf[j] = *(const s16x8*)(qn + qg * 128 + (hg * 4 + j) * 16 + half * 8);
  __syncthreads();

  // V transpose: Vraw rows 0..215 -> regs -> Vt [64 ch][512B sigma(tok)]
  u32 tr[16];
#pragma unroll
  for (int k = 0; k < 8; ++k) {
    int u = tid + 448 * k;
    if (u < 3456) {
      int t = (u >> 5) * 2, c2 = u & 31;
      tr[2 * k]     = *(const u32*)(smem + VHOFF + t * 128 + c2 * 4);
      tr[2 * k + 1] = *(const u32*)(smem + VHOFF + t * 128 + 128 + c2 * 4);
    }
  }
  __syncthreads();
#pragma unroll
  for (int k = 0; k < 8; ++k) {
    int u = tid + 448 * k;
    if (u < 3456) {
      int t = (u >> 5) * 2, c2 = u & 31;
      int st = (t & ~12) | ((t & 4) << 1) | ((t & 8) >> 1);
      int c = 2 * c2;
      u32 w0 = (tr[2 * k] & 0xFFFFu) | (tr[2 * k + 1] << 16);
      u32 w1 = (tr[2 * k] >> 16) | (tr[2 * k + 1] & 0xFFFF0000u);
      *(u32*)(smem + VHOFF + c * 512 + ((st * 2) ^ ((c & 7) << 4))) = w0;
      *(u32*)(smem + VHOFF + (c + 1) * 512 + ((st * 2) ^ (((c + 1) & 7) << 4))) = w1;
    }
  }
  if (tid < 64) {   // sigma-positions {212-215,220-223} zeroed
    int x = (tid & 7) << 4;
    *(u32*)(smem + VHOFF + tid * 512 + (424 ^ x)) = 0;
    *(u32*)(smem + VHOFF + tid * 512 + (428 ^ x)) = 0;
    *(u32*)(smem + VHOFF + tid * 512 + (440 ^ x)) = 0;
    *(u32*)(smem + VHOFF + tid * 512 + (444 ^ x)) = 0;
  }
  __syncthreads();

  // attention: wave owns q rows [wv*32,+32), 4 heads (2 pairs)
  u32 oPk[4][4];
#pragma unroll
  for (int hp = 0; hp < 2; ++hp) {
    const int j0 = 2 * hp, j1 = j0 + 1;
    f32x16 a0 = {}, a1 = {};
    float l0 = 0.f, l1 = 0.f;
#pragma unroll 2
    for (int kt = 0; kt < 6; ++kt) {
      attn_stepH<false>(smem, j0, kt, qf[j0], lane, a0, l0);
      attn_stepH<false>(smem, j1, kt, qf[j1], lane, a1, l1);
    }
    attn_stepH<true>(smem, j0, 6, qf[j0], lane, a0, l0);
    attn_stepH<true>(smem, j1, 6, qf[j1], lane, a1, l1);
    l0 += __shfl_xor(l0, 32);
    l1 += __shfl_xor(l1, 32);
    float i0 = 1.0f / l0, i1 = 1.0f / l1;
#pragma unroll
    for (int r = 0; r < 4; ++r) {
      oPk[j0][r] = pack2(a0[2 * r] * i0, a0[2 * r + 1] * i0);
      oPk[j1][r] = pack2(a1[2 * r] * i1, a1[2 * r + 1] * i1);
    }
  }
  __syncthreads();   // all K reads done; reuse KH region as obuf

  // obuf: O^T regs -> [tok][128B half-row]
  {
    const int tok = wv * 32 + (lane & 31);
#pragma unroll
    for (int j = 0; j < 4; ++j) {
      int chb = j * 32 + half * 8;
      *(u32*)(smem + tok * 128 + ((chb)      ^ ((tok & 7) << 4))) = oPk[j][0];
      *(u32*)(smem + tok * 128 + ((chb + 4)  ^ ((tok & 7) << 4))) = oPk[j][1];
      *(u32*)(smem + tok * 128 + ((chb + 16) ^ ((tok & 7) << 4))) = oPk[j][2];
      *(u32*)(smem + tok * 128 + ((chb + 20) ^ ((tok & 7) << 4))) = oPk[j][3];
    }
  }
  __syncthreads();

  // stream obuf -> qn (in-place O-half; coalesced 128B pieces)
#pragma unroll
  for (int it = 0; it < 4; ++it) {
    int i = tid + 448 * it;
    int row = i >> 3;
    if (row < 216) {
      int chunk = i & 7;
      f32x4 v = *(const f32x4*)(smem + row * 128 +
                                ((chunk * 16) ^ ((row & 7) << 4)));
      int tq = row / 6;
      int g = (wd6 + tq / 6) * 2304 + (wh6 + tq % 6) * 48 + ww6 + row % 6;
      *(f32x4*)(qn + g * 128 + hg * 64 + chunk * 8) = v;
    }
  }
}

// ================= Kernel 3: projection GEMM + unwindow =====================
extern "C" __global__ __launch_bounds__(256, 3)
void proj_kernel(const u16* __restrict__ on, const u16* __restrict__ wbf,
                 const float* __restrict__ pb, float* __restrict__ out) {
  __shared__ __align__(16) char smem[45056];   // W 32768 + O 12288
  const int tid = threadIdx.x, lane = tid & 63, wv = tid >> 6;
  const int bid = blockIdx.x;
  const int dh = (bid / 48) * 2304 + (bid % 48) * 48;
  for (int uu = wv; uu < 32; uu += 4) {        // W: 128 rows x 256B
    int row = 4 * uu + (lane >> 4);
    gload16(wbf + row * 128 + (((lane & 15) ^ (row & 15)) << 3),
            smem + uu * 1024);
  }
  for (int uu = wv; uu < 12; uu += 4) {        // O: 48 rows x 256B
    int row = 4 * uu + (lane >> 4);
    gload16(on + (long)(dh + row) * 128 + (((lane & 15) ^ (row & 15)) << 3),
            smem + 32768 + uu * 1024);
  }
  __syncthreads();
#pragma unroll
  for (int jj = 0; jj < 2; ++jj) {
    int jt = wv * 2 + jj;
    int rw = jt * 16 + (lane & 15);
    s16x8 af[4];
#pragma unroll
    for (int kk = 0; kk < 4; ++kk)
      af[kk] = *(const s16x8*)(smem + rw * 256 +
                               ((kk * 64 + (lane >> 4) * 16) ^ ((rw & 15) << 4)));
    f32x4 pbv = *(const f32x4*)(pb + jt * 16 + (lane >> 4) * 4);
#pragma unroll
    for (int t = 0; t < 3; ++t) {
      int tok = t * 16 + (lane & 15);
      f32x4 acc = {};
#pragma unroll
      for (int kk = 0; kk < 4; ++kk) {
        s16x8 bfr = *(const s16x8*)(smem + 32768 + tok * 256 +
                                    ((kk * 64 + (lane >> 4) * 16) ^ ((tok & 15) << 4)));
        acc = __builtin_amdgcn_mfma_f32_16x16x32_bf16(af[kk], bfr, acc, 0, 0, 0);
      }
#pragma unroll
      for (int r = 0; r < 4; ++r) {
        int j = jt * 16 + (lane >> 4) * 4 + r;
        out[(long)j * SP + dh + tok] = acc[r] + pbv[r];
      }
    }
  }
}

// ================= Fallback: fused single kernel (r7-r15 verified) ==========
extern "C" __global__ __launch_bounds__(T1, 2)
void ca3d_kernel(const float* __restrict__ qm, const float* __restrict__ km,
                 const float* __restrict__ vm,
                 const float* __restrict__ gq, const float* __restrict__ bq,
                 const float* __restrict__ gkv, const float* __restrict__ bkv,
                 const float* __restrict__ pw, const float* __restrict__ pb,
                 float* __restrict__ out) {
  extern __shared__ __align__(16) char smem[];
  const int tid = threadIdx.x;
  const int lane = tid & 63;
  const int wv = tid >> 6;
  const int bid = blockIdx.x;
  const int wid = ((bid & 7) << 6) | (bid >> 3);
  const int wd = wid >> 6, wh = (wid >> 3) & 7, ww = wid & 7;
  const int boff = wd * 6 * 2304 + wh * 6 * 48 + ww * 6;

  for (int i = tid * 16; i < VOFF + 65536; i += T1 * 16)
    *(f32x4*)(smem + i) = (f32x4){};
  if (tid < 128) {
    ((float*)(smem + GBOFF))[tid] = gq[tid];
    ((float*)(smem + GBOFF + 512))[tid] = bq[tid];
    ((float*)(smem + GBOFF + 1024))[tid] = gkv[tid];
    ((float*)(smem + GBOFF + 1536))[tid] = bkv[tid];
  }
  const bool lnAct = tid < 432;
  const int tp = tid >> 2;
  const int cbase = (tid & 3) * 32;
  const int tA = tp * 2, tB = tA + 1;
  int td = tA / 36, tr_ = tA - td * 36;
  int th_ = tr_ / 6, tw_ = tr_ - th_ * 6;
  const int gpos = boff + td * 2304 + th_ * 48 + tw_;
  const int vposA = (tA & ~0xC) | ((tA & 4) << 1) | ((tA & 8) >> 1);

  f32x2 qv[32], kv[32], vv[32];
  if (lnAct) {
#pragma unroll
    for (int c = 0; c < 32; ++c)
      qv[c] = *(const f32x2*)(qm + gpos + (cbase + c) * SP);
#pragma unroll
    for (int c = 0; c < 32; ++c)
      kv[c] = *(const f32x2*)(km + gpos + (cbase + c) * SP);
  }
  __syncthreads();
  const float* gql = (const float*)(smem + GBOFF);
  const float* bql = (const float*)(smem + GBOFF + 512);
  const float* gkl = (const float*)(smem + GBOFF + 1024);
  const float* bkl = (const float*)(smem + GBOFF + 1536);
  if (lnAct) {
    float mA, rA, mB, rB;
    ln_stats(qv, mA, rA, mB, rB);
#pragma unroll
    for (int c = 0; c < 32; c += 2) {
      int cc = cbase + c;
      float g0 = gql[cc], g1 = gql[cc + 1], b0 = bql[cc], b1 = bql[cc + 1];
      *(u32*)(smem + BUF0 + tA * 256 + swz(tA, cc * 2)) =
          pack2(((qv[c].x - mA) * rA * g0 + b0) * QSCALE,
                ((qv[c + 1].x - mA) * rA * g1 + b1) * QSCALE);
      *(u32*)(smem + BUF0 + tB * 256 + swz(tB, cc * 2)) =
          pack2(((qv[c].y - mB) * rB * g0 + b0) * QSCALE,
                ((qv[c + 1].y - mB) * rB * g1 + b1) * QSCALE);
    }
#pragma unroll
    for (int c = 0; c < 32; ++c)
      vv[c] = *(const f32x2*)(vm + gpos + (cbase + c) * SP);
  }
  __syncthreads();
  s16x8 qf[8];
  {
    int row = wv * 32 + (lane & 31);
    int ib = (lane >> 5) * 16;
#pragma unroll
    for (int h = 0; h < 8; ++h)
      qf[h] = *(const s16x8*)(smem + BUF0 + row * 256 + swz(row, h * 32 + ib));
  }
  __syncthreads();
  if (lnAct) {
    {
      float mA, rA, mB, rB;
      ln_stats(kv, mA, rA, mB, rB);
#pragma unroll
      for (int c = 0; c < 32; c += 2) {
        int cc = cbase + c;
        float g0 = gkl[cc], g1 = gkl[cc + 1], b0 = bkl[cc], b1 = bkl[cc + 1];
        *(u32*)(smem + BUF0 + tA * 256 + swz(tA, cc * 2)) =
            pack2((kv[c].x - mA) * rA * g0 + b0,
                  (kv[c + 1].x - mA) * rA * g1 + b1);
        *(u32*)(smem + BUF0 + tB * 256 + swz(tB, cc * 2)) =
            pack2((kv[c].y - mB) * rB * g0 + b0,
                  (kv[c + 1].y - mB) * rB * g1 + b1);
      }
    }
    {
      float mA, rA, mB, rB;
      ln_stats(vv, mA, rA, mB, rB);
#pragma unroll
      for (int c = 0; c < 32; ++c) {
        int cc = cbase + c;
        float g0 = gkl[cc], b0 = bkl[cc];
        *(u32*)(smem + VOFF + cc * 512 + swz(cc, vposA * 2)) =
            pack2((vv[c].x - mA) * rA * g0 + b0,
                  (vv[c].y - mB) * rB * g0 + b0);
      }
    }
  }
  for (int i = tid; i < 8192; i += T1) {
    int j = i >> 6, c2 = i & 63;
    f32x2 w2 = *(const f32x2*)(pw + j * 128 + c2 * 2);
    *(u32*)(smem + WOFF + j * 256 + swz(j, c2 * 4)) = pack2(w2.x, w2.y);
  }
  __syncthreads();
  u32 oPk[8][4];
#pragma unroll
  for (int hp = 0; hp < 4; ++hp) {
    const int h0 = hp * 2, h1 = h0 + 1;
    f32x16 a0 = {}, a1 = {};
    float l0 = 0.f, l1 = 0.f;
#pragma unroll 1
    for (int kt = 0; kt < 6; ++kt) {
      attn_stepF<false>(smem, h0, kt, qf[h0], lane, a0, l0);
      attn_stepF<false>(smem, h1, kt, qf[h1], lane, a1, l1);
    }
    attn_stepF<true>(smem, h0, 6, qf[h0], lane, a0, l0);
    attn_stepF<true>(smem, h1, 6, qf[h1], lane, a1, l1);
    l0 += __shfl_xor(l0, 32);
    l1 += __shfl_xor(l1, 32);
    float i0 = 1.0f / l0, i1 = 1.0f / l1;
#pragma unroll
    for (int r = 0; r < 4; ++r) {
      oPk[h0][r] = pack2(a0[2 * r] * i0, a0[2 * r + 1] * i0);
      oPk[h1][r] = pack2(a1[2 * r] * i1, a1[2 * r + 1] * i1);
    }
  }
  __syncthreads();
  {
    const int tok = wv * 32 + (lane & 31);
    const int half = lane >> 5;
#pragma unroll
    for (int h = 0; h < 8; ++h) {
      int chb = h * 32 + half * 8;
      *(u32*)(smem + BUF0 + tok * 256 + swz(tok, chb))      = oPk[h][0];
      *(u32*)(smem + BUF0 + tok * 256 + swz(tok, chb + 4))  = oPk[h][1];
      *(u32*)(smem + BUF0 + tok * 256 + swz(tok, chb + 16)) = oPk[h][2];
      *(u32*)(smem + BUF0 + tok * 256 + swz(tok, chb + 20)) = oPk[h][3];
    }
  }
  __syncthreads();
#pragma unroll 1
  for (int ti = 0; ti < 2; ++ti) {
    int tt = wv * 2 + ti;
    int tok = tt * 16 + (lane & 15);
    s16x8 bfr[4];
#pragma unroll
    for (int kk = 0; kk < 4; ++kk)
      bfr[kk] = *(const s16x8*)(smem + BUF0 + tok * 256 +
                                swz(tok, kk * 64 + (lane >> 4) * 16));
    bool tokValid = tok < TOK;
    int tdd = tok / 36, trr = tok - tdd * 36;
    int thh = trr / 6, tww = trr - thh * 6;
    int pos = boff + tdd * 2304 + thh * 48 + tww;
#pragma unroll 1
    for (int jt = 0; jt < 8; ++jt) {
      f32x4 acc = {};
#pragma unroll
      for (int kk = 0; kk < 4; ++kk) {
        int rw = jt * 16 + (lane & 15);
        s16x8 af = *(const s16x8*)(smem + WOFF + rw * 256 +
                                   swz(rw, kk * 64 + (lane >> 4) * 16));
        acc = __builtin_amdgcn_mfma_f32_16x16x32_bf16(af, bfr[kk], acc, 0, 0, 0);
      }
      f32x4 pbv = *(const f32x4*)(pb + jt * 16 + (lane >> 4) * 4);
      if (tokValid) {
#pragma unroll
        for (int r = 0; r < 4; ++r) {
          int j = jt * 16 + (lane >> 4) * 4 + r;
          out[j * SP + pos] = acc[r] + pbv[r];
        }
      }
    }
  }
}

extern "C" void kernel_launch(void* const* d_in, const int* in_sizes, int n_in,
                              void* d_out, int out_size, void* d_ws, size_t ws_size,
                              hipStream_t stream) {
  const float* qm  = (const float*)d_in[0];
  const float* km  = (const float*)d_in[1];
  const float* vm  = (const float*)d_in[2];
  const float* gq  = (const float*)d_in[3];
  const float* bq  = (const float*)d_in[4];
  const float* gkv = (const float*)d_in[5];
  const float* bkv = (const float*)d_in[6];
  const float* pw  = (const float*)d_in[7];
  const float* pb  = (const float*)d_in[8];
  if (ws_size >= WSNEED) {
    u16* qn  = (u16*)d_ws;                       // Q, then O in-place
    u16* kn  = (u16*)((char*)d_ws + TENB);
    u16* vn  = (u16*)((char*)d_ws + 2 * TENB);
    u16* wbf = (u16*)((char*)d_ws + 3 * TENB);
    hipLaunchKernelGGL(lnpre_kernel, dim3(2593), dim3(128), 0, stream,
                       qm, km, vm, gq, bq, gkv, bkv, pw, qn, kn, vn, wbf);
    hipLaunchKernelGGL(attnh_kernel, dim3(1024), dim3(448), 0, stream,
                       qn, kn, vn);
    hipLaunchKernelGGL(proj_kernel, dim3(2304), dim3(256), 0, stream,
                       qn, wbf, pb, (float*)d_out);
  } else {
    hipLaunchKernelGGL(ca3d_kernel, dim3(512), dim3(T1), LDS_OLD, stream,
                       qm, km, vm, gq, bq, gkv, bkv, pw, pb, (float*)d_out);
  }
}

// Round 17
// 136.431 us; speedup vs baseline: 1.2307x; 1.2307x over previous
//
#include <hip/hip_runtime.h>
#include <hip/hip_bf16.h>

typedef short s16x8 __attribute__((ext_vector_type(8)));
typedef float f32x2 __attribute__((ext_vector_type(2)));
typedef float f32x4 __attribute__((ext_vector_type(4)));
typedef float f32x16 __attribute__((ext_vector_type(16)));
typedef unsigned int u32;
typedef unsigned short u16;
typedef u32 u32x4v __attribute__((ext_vector_type(4)));

#define TOK 216
#define T1 448
#define SP 110592
// fallback LDS map
#define BUF0 0
#define VOFF 57344
#define WOFF 122880
#define GBOFF 155648
#define LDS_OLD 157696
// attnh LDS map: KH [224 rows x 128B] then obuf; VHOFF Vraw(27KB)->Vt 64x512B
#define VHOFF 28672
#define TENB 28311552ull
#define WSNEED (3ull*TENB + 32768ull)
#define QSCALE 0.360673760f // 0.25 * log2(e): scores*log2e -> exp2

__device__ __forceinline__ u32 pack2(float a, float b) {
  u16 lo = __builtin_bit_cast(u16, __float2bfloat16(a));
  u16 hi = __builtin_bit_cast(u16, __float2bfloat16(b));
  return (u32)lo | ((u32)hi << 16);
}
__device__ __forceinline__ int swz(int row, int inner) {
  return inner ^ ((row & 7) << 4);
}
__device__ __forceinline__ void gload16(const void* g, void* l) {
  __builtin_amdgcn_global_load_lds(
      (const __attribute__((address_space(1))) void*)g,
      (__attribute__((address_space(3))) void*)l, 16, 0, 0);
}

__device__ __forceinline__ void ln_stats(const f32x2* xv, float& mA, float& rA,
                                         float& mB, float& rB) {
  float sA = 0.f, s2A = 0.f, sB = 0.f, s2B = 0.f;
#pragma unroll
  for (int c = 0; c < 32; ++c) {
    sA += xv[c].x; s2A += xv[c].x * xv[c].x;
    sB += xv[c].y; s2B += xv[c].y * xv[c].y;
  }
  sA += __shfl_xor(sA, 1); s2A += __shfl_xor(s2A, 1);
  sB += __shfl_xor(sB, 1); s2B += __shfl_xor(s2B, 1);
  sA += __shfl_xor(sA, 2); s2A += __shfl_xor(s2A, 2);
  sB += __shfl_xor(sB, 2); s2B += __shfl_xor(s2B, 2);
  mA = sA * (1.0f / 128.0f);
  rA = rsqrtf(s2A * (1.0f / 128.0f) - mA * mA + 1e-5f);
  mB = sB * (1.0f / 128.0f);
  rB = rsqrtf(s2B * (1.0f / 128.0f) - mB * mB + 1e-5f);
}

// attnh step: head-half tiles (K rows 128B, V-half 64 ch-rows). Verified
// r6-r14 math with half-width indexing. No-max softmax (exp2, log2e in Q);
// sigma-permuted V so packed P regs ARE the PV B-fragments.
template<bool MASK>
__device__ __forceinline__ void attn_stepH(const char* smem, int jloc, int kt,
                                           s16x8 qfh, int lane,
                                           f32x16& acc, float& lsum) {
  const int half = lane >> 5;
  const int krow = kt * 32 + (lane & 31);
  s16x8 kf = *(const s16x8*)(smem + krow * 128 +
                             ((jloc * 32 + half * 16) ^ ((krow & 7) << 4)));
  f32x16 st = __builtin_amdgcn_mfma_f32_32x32x16_bf16(kf, qfh, (f32x16){}, 0, 0, 0);
  const int vrow = jloc * 16 + (lane & 15);
  s16x8 vf0 = *(const s16x8*)(smem + VHOFF + vrow * 512 +
                              ((kt * 64 + half * 16) ^ ((vrow & 7) << 4)));
  s16x8 vf1 = *(const s16x8*)(smem + VHOFF + vrow * 512 +
                              ((kt * 64 + 32 + half * 16) ^ ((vrow & 7) << 4)));
  const int NR = MASK ? 12 : 16;
  u32 A[8];
  float ts0 = 0.f, ts1 = 0.f;
#pragma unroll
  for (int i = 0; i < 8; ++i) {
    float p0 = (2 * i < NR) ? __builtin_amdgcn_exp2f(st[2 * i]) : 0.f;
    float p1 = (2 * i + 1 < NR) ? __builtin_amdgcn_exp2f(st[2 * i + 1]) : 0.f;
    if (i & 1) ts1 += p0 + p1; else ts0 += p0 + p1;
    A[i] = pack2(p0, p1);
  }
  lsum += ts0 + ts1;
  s16x8 pf0 = __builtin_bit_cast(s16x8, (u32x4v){A[0], A[1], A[2], A[3]});
  s16x8 pf1 = __builtin_bit_cast(s16x8, (u32x4v){A[4], A[5], A[6], A[7]});
  acc = __builtin_amdgcn_mfma_f32_32x32x16_bf16(vf0, pf0, acc, 0, 0, 0);
  acc = __builtin_amdgcn_mfma_f32_32x32x16_bf16(vf1, pf1, acc, 0, 0, 0);
}

// fallback step (verified r6-r14)
template<bool MASK>
__device__ __forceinline__ void attn_stepF(const char* smem, int h, int kt,
                                           s16x8 qfh, int lane,
                                           f32x16& acc, float& lsum) {
  const int half = lane >> 5;
  const int krow = kt * 32 + (lane & 31);
  s16x8 kf = *(const s16x8*)(smem + BUF0 + krow * 256 +
                             swz(krow, h * 32 + half * 16));
  f32x16 st = __builtin_amdgcn_mfma_f32_32x32x16_bf16(kf, qfh, (f32x16){}, 0, 0, 0);
  const int vrow = h * 16 + (lane & 15);
  s16x8 vf0 = *(const s16x8*)(smem + VOFF + vrow * 512 +
                              swz(vrow, kt * 64 + half * 16));
  s16x8 vf1 = *(const s16x8*)(smem + VOFF + vrow * 512 +
                              swz(vrow, kt * 64 + 32 + half * 16));
  const int NR = MASK ? 12 : 16;
  u32 A[8];
  float ts0 = 0.f, ts1 = 0.f;
#pragma unroll
  for (int i = 0; i < 8; ++i) {
    float p0 = (2 * i < NR) ? __builtin_amdgcn_exp2f(st[2 * i]) : 0.f;
    float p1 = (2 * i + 1 < NR) ? __builtin_amdgcn_exp2f(st[2 * i + 1]) : 0.f;
    if (i & 1) ts1 += p0 + p1; else ts0 += p0 + p1;
    A[i] = pack2(p0, p1);
  }
  lsum += ts0 + ts1;
  s16x8 pf0 = __builtin_bit_cast(s16x8, (u32x4v){A[0], A[1], A[2], A[3]});
  s16x8 pf1 = __builtin_bit_cast(s16x8, (u32x4v){A[4], A[5], A[6], A[7]});
  acc = __builtin_amdgcn_mfma_f32_32x32x16_bf16(vf0, pf0, acc, 0, 0, 0);
  acc = __builtin_amdgcn_mfma_f32_32x32x16_bf16(vf1, pf1, acc, 0, 0, 0);
}

// ================= Kernel 1: LN over contiguous 144-token spans =============
// (round-14 verified config: total 136.1us, lnpre ~86us -- best of 5 measured
// lnpre structures; the channel-strided read pattern plateaus at ~2.9 TB/s
// effective across ALL structural variants tested in r12-r16.)
extern "C" __global__ __launch_bounds__(256)
void lnpre_kernel(const float* __restrict__ qm, const float* __restrict__ km,
                  const float* __restrict__ vm,
                  const float* __restrict__ gq, const float* __restrict__ bq,
                  const float* __restrict__ gkv, const float* __restrict__ bkv,
                  const float* __restrict__ pw,
                  u16* __restrict__ qn, u16* __restrict__ kn,
                  u16* __restrict__ vn, u16* __restrict__ wbf) {
  const int tid = threadIdx.x;
  const int bid = blockIdx.x;
  if (bid >= 2304) {            // W conversion: 16384 f32 -> bf16
#pragma unroll
    for (int k = 0; k < 32; ++k) {
      int idx = tid + 256 * k;
      f32x2 w2 = *(const f32x2*)(pw + idx * 2);
      ((u32*)wbf)[idx] = pack2(w2.x, w2.y);
    }
    return;
  }
  __shared__ __align__(16) float lf[18432];   // [128 ch][144 tok] fp32
  __shared__ float gl[128], bl[128];
  const int t = bid / 768, span = bid - t * 768;
  const float* src = t == 0 ? qm : (t == 1 ? km : vm);
  u16* dst = t == 0 ? qn : (t == 1 ? kn : vn);
  const float* gsrc = (t == 0) ? gq : gkv;
  const float* bsrc = (t == 0) ? bq : bkv;
  const float scale = (t == 0) ? QSCALE : 1.0f;
  const int T0 = span * 144;                  // global token base
  const int lane = tid & 63, wv = tid >> 6;

  if (tid < 128) { gl[tid] = gsrc[tid]; bl[tid] = bsrc[tid]; }
  // stage 72KB: unit j (16B) -> lf byte j*16 ; j = ch*36 + u, src run 576B/ch
  for (int uu = wv; uu < 72; uu += 4) {
    int j = uu * 64 + lane;
    int ch = j / 36, u = j - ch * 36;
    gload16(src + (long)ch * SP + T0 + u * 4, (char*)lf + uu * 1024);
  }
  __syncthreads();

  // LN: task = (token i in span, ch-quadrant q); 576 tasks over 3 rounds
#pragma unroll 1
  for (int z = 0; z < 3; ++z) {
    int task = z * 256 + tid;
    if (task < 576) {
      const int i = task >> 2, q = task & 3;
      float s = 0.f, s2 = 0.f;
#pragma unroll
      for (int c = 0; c < 32; ++c) {
        float x = lf[(q + 4 * c) * 144 + i];
        s += x; s2 += x * x;
      }
      s += __shfl_xor(s, 1); s2 += __shfl_xor(s2, 1);
      s += __shfl_xor(s, 2); s2 += __shfl_xor(s2, 2);
      float m = s * (1.f / 128.f);
      float r = rsqrtf(s2 * (1.f / 128.f) - m * m + 1e-5f);
      u32x4v* op = (u32x4v*)(dst + (long)(T0 + i) * 128 + 32 * q);
#pragma unroll
      for (int v4 = 0; v4 < 4; ++v4) {
        u32x4v pk;
#pragma unroll
        for (int e = 0; e < 4; ++e) {
          int ch = 32 * q + v4 * 8 + 2 * e;
          float y0 = ((lf[ch * 144 + i] - m) * r * gl[ch] + bl[ch]) * scale;
          float y1 = ((lf[(ch + 1) * 144 + i] - m) * r * gl[ch + 1] + bl[ch + 1]) * scale;
          pk[e] = pack2(y0, y1);
        }
        op[v4] = pk;
      }
    }
  }
}

// ================= Kernel 2: attention, (window x head-half) blocks =========
// 1024 blocks x 448 threads, 61440B LDS -> 2 blocks/CU. O-half streamed
// coalesced into qn in-place (block only overwrites rows/bytes only it reads).
extern "C" __global__ __launch_bounds__(448, 4)
void attnh_kernel(u16* __restrict__ qn, const u16* __restrict__ kn,
                  const u16* __restrict__ vn) {
  __shared__ __align__(16) char smem[61440];
  const int tid = threadIdx.x, lane = tid & 63, wv = tid >> 6;
  const int half = lane >> 5;
  const int bid = blockIdx.x;
  const int wid = bid >> 1, hg = bid & 1;
  const int wd6 = (wid >> 6) * 6, wh6 = ((wid >> 3) & 7) * 6, ww6 = (wid & 7) * 6;

  // stage K-half (swz-src, 8 rows x 128B per unit)
  for (int uu = wv; uu < 27; uu += 7) {
    int row = 8 * uu + (lane >> 3);
    int tq = row / 6;
    int g = (wd6 + tq / 6) * 2304 + (wh6 + tq % 6) * 48 + ww6 + row % 6;
    gload16(kn + g * 128 + hg * 64 + (((lane & 7) ^ (row & 7)) << 3),
            smem + uu * 1024);
  }
  // stage V-half raw (linear rows [tok][64ch])
  for (int uu = wv; uu < 27; uu += 7) {
    int row = 8 * uu + (lane >> 3);
    int tq = row / 6;
    int g = (wd6 + tq / 6) * 2304 + (wh6 + tq % 6) * 48 + ww6 + row % 6;
    gload16(vn + g * 128 + hg * 64 + ((lane & 7) << 3),
            smem + VHOFF + uu * 1024);
  }
  // Q fragments direct from global (drain overlaps K/V staging)
  int qrow = wv * 32 + (lane & 31);
  if (qrow > 215) qrow = 215;
  int qtq = qrow / 6;
  int qg = (wd6 + qtq / 6) * 2304 + (wh6 + qtq % 6) * 48 + ww6 + qrow % 6;
  s16x8 qf[4];
#pragma unroll
  for (int j = 0; j < 4; ++j)
    qf[j] = *(const s16x8*)(qn + qg * 128 + (hg * 4 + j) * 16 + half * 8);
  __syncthreads();

  // V transpose: Vraw rows 0..215 -> regs -> Vt [64 ch][512B sigma(tok)]
  u32 tr[16];
#pragma unroll
  for (int k = 0; k < 8; ++k) {
    int u = tid + 448 * k;
    if (u < 3456) {
      int t = (u >> 5) * 2, c2 = u & 31;
      tr[2 * k]     = *(const u32*)(smem + VHOFF + t * 128 + c2 * 4);
      tr[2 * k + 1] = *(const u32*)(smem + VHOFF + t * 128 + 128 + c2 * 4);
    }
  }
  __syncthreads();
#pragma unroll
  for (int k = 0; k < 8; ++k) {
    int u = tid + 448 * k;
    if (u < 3456) {
      int t = (u >> 5) * 2, c2 = u & 31;
      int st = (t & ~12) | ((t & 4) << 1) | ((t & 8) >> 1);
      int c = 2 * c2;
      u32 w0 = (tr[2 * k] & 0xFFFFu) | (tr[2 * k + 1] << 16);
      u32 w1 = (tr[2 * k] >> 16) | (tr[2 * k + 1] & 0xFFFF0000u);
      *(u32*)(smem + VHOFF + c * 512 + ((st * 2) ^ ((c & 7) << 4))) = w0;
      *(u32*)(smem + VHOFF + (c + 1) * 512 + ((st * 2) ^ (((c + 1) & 7) << 4))) = w1;
    }
  }
  if (tid < 64) {   // sigma-positions {212-215,220-223} zeroed
    int x = (tid & 7) << 4;
    *(u32*)(smem + VHOFF + tid * 512 + (424 ^ x)) = 0;
    *(u32*)(smem + VHOFF + tid * 512 + (428 ^ x)) = 0;
    *(u32*)(smem + VHOFF + tid * 512 + (440 ^ x)) = 0;
    *(u32*)(smem + VHOFF + tid * 512 + (444 ^ x)) = 0;
  }
  __syncthreads();

  // attention: wave owns q rows [wv*32,+32), 4 heads (2 pairs)
  u32 oPk[4][4];
#pragma unroll
  for (int hp = 0; hp < 2; ++hp) {
    const int j0 = 2 * hp, j1 = j0 + 1;
    f32x16 a0 = {}, a1 = {};
    float l0 = 0.f, l1 = 0.f;
#pragma unroll 2
    for (int kt = 0; kt < 6; ++kt) {
      attn_stepH<false>(smem, j0, kt, qf[j0], lane, a0, l0);
      attn_stepH<false>(smem, j1, kt, qf[j1], lane, a1, l1);
    }
    attn_stepH<true>(smem, j0, 6, qf[j0], lane, a0, l0);
    attn_stepH<true>(smem, j1, 6, qf[j1], lane, a1, l1);
    l0 += __shfl_xor(l0, 32);
    l1 += __shfl_xor(l1, 32);
    float i0 = 1.0f / l0, i1 = 1.0f / l1;
#pragma unroll
    for (int r = 0; r < 4; ++r) {
      oPk[j0][r] = pack2(a0[2 * r] * i0, a0[2 * r + 1] * i0);
      oPk[j1][r] = pack2(a1[2 * r] * i1, a1[2 * r + 1] * i1);
    }
  }
  __syncthreads();   // all K reads done; reuse KH region as obuf

  // obuf: O^T regs -> [tok][128B half-row]
  {
    const int tok = wv * 32 + (lane & 31);
#pragma unroll
    for (int j = 0; j < 4; ++j) {
      int chb = j * 32 + half * 8;
      *(u32*)(smem + tok * 128 + ((chb)      ^ ((tok & 7) << 4))) = oPk[j][0];
      *(u32*)(smem + tok * 128 + ((chb + 4)  ^ ((tok & 7) << 4))) = oPk[j][1];
      *(u32*)(smem + tok * 128 + ((chb + 16) ^ ((tok & 7) << 4))) = oPk[j][2];
      *(u32*)(smem + tok * 128 + ((chb + 20) ^ ((tok & 7) << 4))) = oPk[j][3];
    }
  }
  __syncthreads();

  // stream obuf -> qn (in-place O-half; coalesced 128B pieces)
#pragma unroll
  for (int it = 0; it < 4; ++it) {
    int i = tid + 448 * it;
    int row = i >> 3;
    if (row < 216) {
      int chunk = i & 7;
      f32x4 v = *(const f32x4*)(smem + row * 128 +
                                ((chunk * 16) ^ ((row & 7) << 4)));
      int tq = row / 6;
      int g = (wd6 + tq / 6) * 2304 + (wh6 + tq % 6) * 48 + ww6 + row % 6;
      *(f32x4*)(qn + g * 128 + hg * 64 + chunk * 8) = v;
    }
  }
}

// ================= Kernel 3: projection GEMM + unwindow =====================
extern "C" __global__ __launch_bounds__(256, 3)
void proj_kernel(const u16* __restrict__ on, const u16* __restrict__ wbf,
                 const float* __restrict__ pb, float* __restrict__ out) {
  __shared__ __align__(16) char smem[45056];   // W 32768 + O 12288
  const int tid = threadIdx.x, lane = tid & 63, wv = tid >> 6;
  const int bid = blockIdx.x;
  const int dh = (bid / 48) * 2304 + (bid % 48) * 48;
  for (int uu = wv; uu < 32; uu += 4) {        // W: 128 rows x 256B
    int row = 4 * uu + (lane >> 4);
    gload16(wbf + row * 128 + (((lane & 15) ^ (row & 15)) << 3),
            smem + uu * 1024);
  }
  for (int uu = wv; uu < 12; uu += 4) {        // O: 48 rows x 256B
    int row = 4 * uu + (lane >> 4);
    gload16(on + (long)(dh + row) * 128 + (((lane & 15) ^ (row & 15)) << 3),
            smem + 32768 + uu * 1024);
  }
  __syncthreads();
#pragma unroll
  for (int jj = 0; jj < 2; ++jj) {
    int jt = wv * 2 + jj;
    int rw = jt * 16 + (lane & 15);
    s16x8 af[4];
#pragma unroll
    for (int kk = 0; kk < 4; ++kk)
      af[kk] = *(const s16x8*)(smem + rw * 256 +
                               ((kk * 64 + (lane >> 4) * 16) ^ ((rw & 15) << 4)));
    f32x4 pbv = *(const f32x4*)(pb + jt * 16 + (lane >> 4) * 4);
#pragma unroll
    for (int t = 0; t < 3; ++t) {
      int tok = t * 16 + (lane & 15);
      f32x4 acc = {};
#pragma unroll
      for (int kk = 0; kk < 4; ++kk) {
        s16x8 bfr = *(const s16x8*)(smem + 32768 + tok * 256 +
                                    ((kk * 64 + (lane >> 4) * 16) ^ ((tok & 15) << 4)));
        acc = __builtin_amdgcn_mfma_f32_16x16x32_bf16(af[kk], bfr, acc, 0, 0, 0);
      }
#pragma unroll
      for (int r = 0; r < 4; ++r) {
        int j = jt * 16 + (lane >> 4) * 4 + r;
        out[(long)j * SP + dh + tok] = acc[r] + pbv[r];
      }
    }
  }
}

// ================= Fallback: fused single kernel (r7-r14 verified) ==========
extern "C" __global__ __launch_bounds__(T1, 2)
void ca3d_kernel(const float* __restrict__ qm, const float* __restrict__ km,
                 const float* __restrict__ vm,
                 const float* __restrict__ gq, const float* __restrict__ bq,
                 const float* __restrict__ gkv, const float* __restrict__ bkv,
                 const float* __restrict__ pw, const float* __restrict__ pb,
                 float* __restrict__ out) {
  extern __shared__ __align__(16) char smem[];
  const int tid = threadIdx.x;
  const int lane = tid & 63;
  const int wv = tid >> 6;
  const int bid = blockIdx.x;
  const int wid = ((bid & 7) << 6) | (bid >> 3);
  const int wd = wid >> 6, wh = (wid >> 3) & 7, ww = wid & 7;
  const int boff = wd * 6 * 2304 + wh * 6 * 48 + ww * 6;

  for (int i = tid * 16; i < VOFF + 65536; i += T1 * 16)
    *(f32x4*)(smem + i) = (f32x4){};
  if (tid < 128) {
    ((float*)(smem + GBOFF))[tid] = gq[tid];
    ((float*)(smem + GBOFF + 512))[tid] = bq[tid];
    ((float*)(smem + GBOFF + 1024))[tid] = gkv[tid];
    ((float*)(smem + GBOFF + 1536))[tid] = bkv[tid];
  }
  const bool lnAct = tid < 432;
  const int tp = tid >> 2;
  const int cbase = (tid & 3) * 32;
  const int tA = tp * 2, tB = tA + 1;
  int td = tA / 36, tr_ = tA - td * 36;
  int th_ = tr_ / 6, tw_ = tr_ - th_ * 6;
  const int gpos = boff + td * 2304 + th_ * 48 + tw_;
  const int vposA = (tA & ~0xC) | ((tA & 4) << 1) | ((tA & 8) >> 1);

  f32x2 qv[32], kv[32], vv[32];
  if (lnAct) {
#pragma unroll
    for (int c = 0; c < 32; ++c)
      qv[c] = *(const f32x2*)(qm + gpos + (cbase + c) * SP);
#pragma unroll
    for (int c = 0; c < 32; ++c)
      kv[c] = *(const f32x2*)(km + gpos + (cbase + c) * SP);
  }
  __syncthreads();
  const float* gql = (const float*)(smem + GBOFF);
  const float* bql = (const float*)(smem + GBOFF + 512);
  const float* gkl = (const float*)(smem + GBOFF + 1024);
  const float* bkl = (const float*)(smem + GBOFF + 1536);
  if (lnAct) {
    float mA, rA, mB, rB;
    ln_stats(qv, mA, rA, mB, rB);
#pragma unroll
    for (int c = 0; c < 32; c += 2) {
      int cc = cbase + c;
      float g0 = gql[cc], g1 = gql[cc + 1], b0 = bql[cc], b1 = bql[cc + 1];
      *(u32*)(smem + BUF0 + tA * 256 + swz(tA, cc * 2)) =
          pack2(((qv[c].x - mA) * rA * g0 + b0) * QSCALE,
                ((qv[c + 1].x - mA) * rA * g1 + b1) * QSCALE);
      *(u32*)(smem + BUF0 + tB * 256 + swz(tB, cc * 2)) =
          pack2(((qv[c].y - mB) * rB * g0 + b0) * QSCALE,
                ((qv[c + 1].y - mB) * rB * g1 + b1) * QSCALE);
    }
#pragma unroll
    for (int c = 0; c < 32; ++c)
      vv[c] = *(const f32x2*)(vm + gpos + (cbase + c) * SP);
  }
  __syncthreads();
  s16x8 qf[8];
  {
    int row = wv * 32 + (lane & 31);
    int ib = (lane >> 5) * 16;
#pragma unroll
    for (int h = 0; h < 8; ++h)
      qf[h] = *(const s16x8*)(smem + BUF0 + row * 256 + swz(row, h * 32 + ib));
  }
  __syncthreads();
  if (lnAct) {
    {
      float mA, rA, mB, rB;
      ln_stats(kv, mA, rA, mB, rB);
#pragma unroll
      for (int c = 0; c < 32; c += 2) {
        int cc = cbase + c;
        float g0 = gkl[cc], g1 = gkl[cc + 1], b0 = bkl[cc], b1 = bkl[cc + 1];
        *(u32*)(smem + BUF0 + tA * 256 + swz(tA, cc * 2)) =
            pack2((kv[c].x - mA) * rA * g0 + b0,
                  (kv[c + 1].x - mA) * rA * g1 + b1);
        *(u32*)(smem + BUF0 + tB * 256 + swz(tB, cc * 2)) =
            pack2((kv[c].y - mB) * rB * g0 + b0,
                  (kv[c + 1].y - mB) * rB * g1 + b1);
      }
    }
    {
      float mA, rA, mB, rB;
      ln_stats(vv, mA, rA, mB, rB);
#pragma unroll
      for (int c = 0; c < 32; ++c) {
        int cc = cbase + c;
        float g0 = gkl[cc], b0 = bkl[cc];
        *(u32*)(smem + VOFF + cc * 512 + swz(cc, vposA * 2)) =
            pack2((vv[c].x - mA) * rA * g0 + b0,
                  (vv[c].y - mB) * rB * g0 + b0);
      }
    }
  }
  for (int i = tid; i < 8192; i += T1) {
    int j = i >> 6, c2 = i & 63;
    f32x2 w2 = *(const f32x2*)(pw + j * 128 + c2 * 2);
    *(u32*)(smem + WOFF + j * 256 + swz(j, c2 * 4)) = pack2(w2.x, w2.y);
  }
  __syncthreads();
  u32 oPk[8][4];
#pragma unroll
  for (int hp = 0; hp < 4; ++hp) {
    const int h0 = hp * 2, h1 = h0 + 1;
    f32x16 a0 = {}, a1 = {};
    float l0 = 0.f, l1 = 0.f;
#pragma unroll 1
    for (int kt = 0; kt < 6; ++kt) {
      attn_stepF<false>(smem, h0, kt, qf[h0], lane, a0, l0);
      attn_stepF<false>(smem, h1, kt, qf[h1], lane, a1, l1);
    }
    attn_stepF<true>(smem, h0, 6, qf[h0], lane, a0, l0);
    attn_stepF<true>(smem, h1, 6, qf[h1], lane, a1, l1);
    l0 += __shfl_xor(l0, 32);
    l1 += __shfl_xor(l1, 32);
    float i0 = 1.0f / l0, i1 = 1.0f / l1;
#pragma unroll
    for (int r = 0; r < 4; ++r) {
      oPk[h0][r] = pack2(a0[2 * r] * i0, a0[2 * r + 1] * i0);
      oPk[h1][r] = pack2(a1[2 * r] * i1, a1[2 * r + 1] * i1);
    }
  }
  __syncthreads();
  {
    const int tok = wv * 32 + (lane & 31);
    const int half = lane >> 5;
#pragma unroll
    for (int h = 0; h < 8; ++h) {
      int chb = h * 32 + half * 8;
      *(u32*)(smem + BUF0 + tok * 256 + swz(tok, chb))      = oPk[h][0];
      *(u32*)(smem + BUF0 + tok * 256 + swz(tok, chb + 4))  = oPk[h][1];
      *(u32*)(smem + BUF0 + tok * 256 + swz(tok, chb + 16)) = oPk[h][2];
      *(u32*)(smem + BUF0 + tok * 256 + swz(tok, chb + 20)) = oPk[h][3];
    }
  }
  __syncthreads();
#pragma unroll 1
  for (int ti = 0; ti < 2; ++ti) {
    int tt = wv * 2 + ti;
    int tok = tt * 16 + (lane & 15);
    s16x8 bfr[4];
#pragma unroll
    for (int kk = 0; kk < 4; ++kk)
      bfr[kk] = *(const s16x8*)(smem + BUF0 + tok * 256 +
                                swz(tok, kk * 64 + (lane >> 4) * 16));
    bool tokValid = tok < TOK;
    int tdd = tok / 36, trr = tok - tdd * 36;
    int thh = trr / 6, tww = trr - thh * 6;
    int pos = boff + tdd * 2304 + thh * 48 + tww;
#pragma unroll 1
    for (int jt = 0; jt < 8; ++jt) {
      f32x4 acc = {};
#pragma unroll
      for (int kk = 0; kk < 4; ++kk) {
        int rw = jt * 16 + (lane & 15);
        s16x8 af = *(const s16x8*)(smem + WOFF + rw * 256 +
                                   swz(rw, kk * 64 + (lane >> 4) * 16));
        acc = __builtin_amdgcn_mfma_f32_16x16x32_bf16(af, bfr[kk], acc, 0, 0, 0);
      }
      f32x4 pbv = *(const f32x4*)(pb + jt * 16 + (lane >> 4) * 4);
      if (tokValid) {
#pragma unroll
        for (int r = 0; r < 4; ++r) {
          int j = jt * 16 + (lane >> 4) * 4 + r;
          out[j * SP + pos] = acc[r] + pbv[r];
        }
      }
    }
  }
}

extern "C" void kernel_launch(void* const* d_in, const int* in_sizes, int n_in,
                              void* d_out, int out_size, void* d_ws, size_t ws_size,
                              hipStream_t stream) {
  const float* qm  = (const float*)d_in[0];
  const float* km  = (const float*)d_in[1];
  const float* vm  = (const float*)d_in[2];
  const float* gq  = (const float*)d_in[3];
  const float* bq  = (const float*)d_in[4];
  const float* gkv = (const float*)d_in[5];
  const float* bkv = (const float*)d_in[6];
  const float* pw  = (const float*)d_in[7];
  const float* pb  = (const float*)d_in[8];
  if (ws_size >= WSNEED) {
    u16* qn  = (u16*)d_ws;                       // Q, then O in-place
    u16* kn  = (u16*)((char*)d_ws + TENB);
    u16* vn  = (u16*)((char*)d_ws + 2 * TENB);
    u16* wbf = (u16*)((char*)d_ws + 3 * TENB);
    hipLaunchKernelGGL(lnpre_kernel, dim3(2305), dim3(256), 0, stream,
                       qm, km, vm, gq, bq, gkv, bkv, pw, qn, kn, vn, wbf);
    hipLaunchKernelGGL(attnh_kernel, dim3(1024), dim3(448), 0, stream,
                       qn, kn, vn);
    hipLaunchKernelGGL(proj_kernel, dim3(2304), dim3(256), 0, stream,
                       qn, wbf, pb, (float*)d_out);
  } else {
    hipLaunchKernelGGL(ca3d_kernel, dim3(512), dim3(T1), LDS_OLD, stream,
                       qm, km, vm, gq, bq, gkv, bkv, pw, pb, (float*)d_out);
  }
}